// Round 1
// baseline (797.919 us; speedup 1.0000x reference)
//
#include <hip/hip_runtime.h>
#include <hip/hip_bf16.h>

// ---------------------------------------------------------------------------
// SimpleRetention, MI355X / gfx950.
// Key insight: the reference decay matrix is all-ones lower-triangular
// (pos_diff = j - i, max(j-i,0)=0 for j<=i), so:
//   out0 = tril(q k^T) v + q @ hstate
//   out1 = k^T v  (+ hstate * 0.9^256 * delta  ~= 2e-12 -> negligible, dones unused)
// Pipeline: proj (q,k,kT,vT bf16) -> transpose hstate -> hstate GEMM -> causal attn.
// ---------------------------------------------------------------------------

#define DEVI __device__ __forceinline__

typedef __bf16 bf16x8 __attribute__((ext_vector_type(8)));
typedef float  f32x4  __attribute__((ext_vector_type(4)));
typedef short  short8 __attribute__((ext_vector_type(8)));

static constexpr int Bn   = 16;
static constexpr int Cn   = 2048;
static constexpr int En   = 1024;
static constexpr int Hn   = 256;

// workspace byte offsets
static constexpr size_t Q_OFF  = 0;                    // [B*C][256] bf16, 16 MB
static constexpr size_t K_OFF  = 16u * 1024 * 1024;    // [B*C][256] bf16
static constexpr size_t KT_OFF = 32u * 1024 * 1024;    // [B][256 h][2048 c] bf16
static constexpr size_t VT_OFF = 48u * 1024 * 1024;    // [B][256 d][2048 c] bf16
static constexpr size_t HT_OFF = 64u * 1024 * 1024;    // [B][256 d][256 h] bf16, 2 MB

DEVI f32x4 MFMA(bf16x8 a, bf16x8 b, f32x4 c) {
  return __builtin_amdgcn_mfma_f32_16x16x32_bf16(a, b, c, 0, 0, 0);
}

DEVI bf16x8 cvt8(float4 f0, float4 f1) {
  bf16x8 o;
  o[0] = (__bf16)f0.x; o[1] = (__bf16)f0.y; o[2] = (__bf16)f0.z; o[3] = (__bf16)f0.w;
  o[4] = (__bf16)f1.x; o[5] = (__bf16)f1.y; o[6] = (__bf16)f1.z; o[7] = (__bf16)f1.w;
  return o;
}

// XOR-swizzled LDS fragment read (row-major tile, rowStride bytes, 16B chunks)
DEVI bf16x8 lds_frag(const char* base, int row, int rowStride, int colByte) {
  return *(const bf16x8*)(base + row * rowStride + (colByte ^ ((row & 7) << 4)));
}
DEVI void lds_put(char* base, int row, int rowStride, int colByte, bf16x8 v) {
  *(bf16x8*)(base + row * rowStride + (colByte ^ ((row & 7) << 4))) = v;
}
DEVI void lds_put_s8(char* base, int row, int rowStride, int colByte, short8 v) {
  *(short8*)(base + row * rowStride + (colByte ^ ((row & 7) << 4))) = v;
}

// ---------------------------------------------------------------------------
// Kernel A: projections. blockIdx.y: 0 -> q (query,wq), 1 -> k (key,wk, +kT),
// 2 -> v (value,wv, vT only). Tile 128(M) x 256(N=all), BK=64, 8 waves.
// ---------------------------------------------------------------------------
__global__ __launch_bounds__(512) void proj_kernel(
    const float* __restrict__ query, const float* __restrict__ key,
    const float* __restrict__ value, const float* __restrict__ wq,
    const float* __restrict__ wk, const float* __restrict__ wv,
    char* __restrict__ ws)
{
  const int mode = blockIdx.y;
  const float* __restrict__ X = (mode == 0) ? query : (mode == 1) ? key : value;
  const float* __restrict__ W = (mode == 0) ? wq    : (mode == 1) ? wk  : wv;

  __shared__ __align__(16) char As[128 * 128];  // 128 rows x 64 bf16 (swizzled)
  __shared__ __align__(16) char Bs[256 * 128];  // 256 rows x 64 bf16

  const int t    = threadIdx.x;
  const int m0   = blockIdx.x * 128;
  const int lane = t & 63, wid = t >> 6;
  const int lr   = lane & 15, lq = lane >> 4;
  const int wr   = wid >> 2, wc = wid & 3;   // wave tile: 64x64 at (wr*64, wc*64)

  f32x4 acc[4][4];
#pragma unroll
  for (int i = 0; i < 4; ++i)
#pragma unroll
    for (int j = 0; j < 4; ++j) acc[i][j] = f32x4{0.f, 0.f, 0.f, 0.f};

  for (int ko = 0; ko < 16; ++ko) {
    const int k0 = ko * 64;
    // stage X tile: 128 x 64 f32 -> bf16
#pragma unroll
    for (int it = 0; it < 2; ++it) {
      int chunk = t + it * 512;
      int row = chunk >> 3, kg = chunk & 7;
      const float4* src = (const float4*)(X + (size_t)(m0 + row) * En + k0 + kg * 8);
      lds_put(As, row, 128, kg * 16, cvt8(src[0], src[1]));
    }
    // stage W tile: 256 x 64 f32 -> bf16  (W is [n][k] row-major: natural)
#pragma unroll
    for (int it = 0; it < 4; ++it) {
      int chunk = t + it * 512;
      int row = chunk >> 3, kg = chunk & 7;
      const float4* src = (const float4*)(W + (size_t)row * En + k0 + kg * 8);
      lds_put(Bs, row, 128, kg * 16, cvt8(src[0], src[1]));
    }
    __syncthreads();
#pragma unroll
    for (int ks = 0; ks < 2; ++ks) {
      const int cb = (ks * 32 + lq * 8) * 2;
      bf16x8 a[4], bb[4];
#pragma unroll
      for (int mf = 0; mf < 4; ++mf) a[mf] = lds_frag(As, wr * 64 + mf * 16 + lr, 128, cb);
#pragma unroll
      for (int nf = 0; nf < 4; ++nf) bb[nf] = lds_frag(Bs, wc * 64 + nf * 16 + lr, 128, cb);
#pragma unroll
      for (int mf = 0; mf < 4; ++mf)
#pragma unroll
        for (int nf = 0; nf < 4; ++nf)
          acc[mf][nf] = MFMA(a[mf], bb[nf], acc[mf][nf]);
    }
    __syncthreads();
  }

  // epilogue: D row = wr*64+mf*16+lq*4+r, col = wc*64+nf*16+lr
#pragma unroll
  for (int mf = 0; mf < 4; ++mf) {
#pragma unroll
    for (int nf = 0; nf < 4; ++nf) {
      const int n = wc * 64 + nf * 16 + lr;
#pragma unroll
      for (int r = 0; r < 4; ++r) {
        const int m = m0 + wr * 64 + mf * 16 + lq * 4 + r;
        const __bf16 s = (__bf16)acc[mf][nf][r];
        if (mode == 0) {
          *(__bf16*)(ws + Q_OFF + ((size_t)m * Hn + n) * 2) = s;
        } else {
          const int b = m >> 11, c = m & 2047;
          if (mode == 1) {
            *(__bf16*)(ws + K_OFF + ((size_t)m * Hn + n) * 2) = s;
            *(__bf16*)(ws + KT_OFF + (((size_t)b * Hn + n) * Cn + c) * 2) = s;
          } else {
            *(__bf16*)(ws + VT_OFF + (((size_t)b * Hn + n) * Cn + c) * 2) = s;
          }
        }
      }
    }
  }
}

// ---------------------------------------------------------------------------
// Kernel D: hstate [b][h][d] f32 -> HT [b][d][h] bf16 (tiny, 4 MB read)
// ---------------------------------------------------------------------------
__global__ void transpose_h(const float* __restrict__ hs, char* __restrict__ ws)
{
  const int tid = blockIdx.x * 256 + threadIdx.x;  // 1,048,576 total
  const int d = tid & 255, h = (tid >> 8) & 255, b = tid >> 16;
  const float v = hs[tid];  // coalesced read (tid == ((b*256+h)*256+d))
  *(__bf16*)(ws + HT_OFF + (((size_t)b * Hn + d) * Hn + h) * 2) = (__bf16)v;
}

// ---------------------------------------------------------------------------
// Kernel B: out1[b] = k[b]^T v[b]  (256x256, K=2048) from kT/vT. 128x128 tile.
// ---------------------------------------------------------------------------
__global__ __launch_bounds__(256, 2) void hstate_kernel(
    const char* __restrict__ ws, float* __restrict__ out)
{
  const int bid = blockIdx.x;               // 16 batches x 2 x 2
  const int b = bid >> 2, ht = (bid >> 1) & 1, dt = bid & 1;
  const int h0 = ht * 128, d0 = dt * 128;

  __shared__ __align__(16) char As[128 * 128];  // kT tile [128 h][64 c]
  __shared__ __align__(16) char Bs[128 * 128];  // vT tile [128 d][64 c]

  const int t = threadIdx.x;
  const int lane = t & 63, wid = t >> 6;
  const int lr = lane & 15, lq = lane >> 4;
  const int wr = wid >> 1, wc = wid & 1;

  const char* kt = ws + KT_OFF + (size_t)b * Hn * Cn * 2;
  const char* vt = ws + VT_OFF + (size_t)b * Hn * Cn * 2;

  f32x4 acc[4][4];
#pragma unroll
  for (int i = 0; i < 4; ++i)
#pragma unroll
    for (int j = 0; j < 4; ++j) acc[i][j] = f32x4{0.f, 0.f, 0.f, 0.f};

  for (int ko = 0; ko < 32; ++ko) {
    const int c0 = ko * 64;
#pragma unroll
    for (int it = 0; it < 4; ++it) {
      int chunk = t + it * 256;
      int row = chunk >> 3, kg = chunk & 7;
      short8 va = *(const short8*)(kt + ((size_t)(h0 + row) * Cn + c0 + kg * 8) * 2);
      lds_put_s8(As, row, 128, kg * 16, va);
      short8 vb = *(const short8*)(vt + ((size_t)(d0 + row) * Cn + c0 + kg * 8) * 2);
      lds_put_s8(Bs, row, 128, kg * 16, vb);
    }
    __syncthreads();
#pragma unroll
    for (int ks = 0; ks < 2; ++ks) {
      const int cb = (ks * 32 + lq * 8) * 2;
      bf16x8 a[4], bb[4];
#pragma unroll
      for (int mf = 0; mf < 4; ++mf) a[mf] = lds_frag(As, wr * 64 + mf * 16 + lr, 128, cb);
#pragma unroll
      for (int nf = 0; nf < 4; ++nf) bb[nf] = lds_frag(Bs, wc * 64 + nf * 16 + lr, 128, cb);
#pragma unroll
      for (int mf = 0; mf < 4; ++mf)
#pragma unroll
        for (int nf = 0; nf < 4; ++nf)
          acc[mf][nf] = MFMA(a[mf], bb[nf], acc[mf][nf]);
    }
    __syncthreads();
  }

  float* o1 = out + (size_t)Bn * Cn * Hn;  // out1 base
#pragma unroll
  for (int mf = 0; mf < 4; ++mf)
#pragma unroll
    for (int nf = 0; nf < 4; ++nf) {
      const int d = d0 + wc * 64 + nf * 16 + lr;
#pragma unroll
      for (int r = 0; r < 4; ++r) {
        const int h = h0 + wr * 64 + mf * 16 + lq * 4 + r;
        o1[((size_t)b * Hn + h) * Hn + d] = acc[mf][nf][r];
      }
    }
}

// ---------------------------------------------------------------------------
// Kernel C: out0[b, i0:i0+64, :] = tril(q k^T) v + q @ hstate.
// 4 waves; wave w owns S columns w*16..w*16+15 and O columns w*64..w*64+63.
// ---------------------------------------------------------------------------
__global__ __launch_bounds__(256, 2) void attn_kernel(
    const char* __restrict__ ws, float* __restrict__ out)
{
  const int bx = 31 - (int)blockIdx.x;   // heavy blocks dispatched first
  const int b  = blockIdx.y;
  const int i0 = bx * 64;
  const int bC = b * Cn;

  __shared__ __align__(16) char Qs[64 * 512];    // [64 i][256 h] bf16, 32 KB
  __shared__ __align__(16) char KVs[256 * 128];  // K:[64 j][256 h]  OR  VT/HT:[256 d][64]
  __shared__ __align__(16) char Ss[64 * 128];    // [64 i][64 j] bf16, 8 KB

  const int t = threadIdx.x;
  const int lane = t & 63, wid = t >> 6;
  const int lr = lane & 15, lq = lane >> 4;

  const char* qws  = ws + Q_OFF;
  const char* kws  = ws + K_OFF;
  const char* vtws = ws + VT_OFF + (size_t)b * Hn * Cn * 2;
  const char* htws = ws + HT_OFF + (size_t)b * Hn * Hn * 2;

  // stage Q tile [64][256]
#pragma unroll
  for (int it = 0; it < 8; ++it) {
    int chunk = t + it * 256;
    int row = chunk >> 5, kg = chunk & 31;
    short8 v = *(const short8*)(qws + ((size_t)(bC + i0 + row) * Hn + kg * 8) * 2);
    lds_put_s8(Qs, row, 512, kg * 16, v);
  }

  f32x4 acc[4][4];
#pragma unroll
  for (int i = 0; i < 4; ++i)
#pragma unroll
    for (int j = 0; j < 4; ++j) acc[i][j] = f32x4{0.f, 0.f, 0.f, 0.f};
  __syncthreads();

  // ---- cross term: O += Q @ hstate, 4 chunks of 64 h ----
  for (int hc = 0; hc < 4; ++hc) {
#pragma unroll
    for (int it = 0; it < 8; ++it) {
      int chunk = t + it * 256;
      int row = chunk >> 3, kg = chunk & 7;   // row = d, cols = h
      short8 v = *(const short8*)(htws + ((size_t)row * Hn + hc * 64 + kg * 8) * 2);
      lds_put_s8(KVs, row, 128, kg * 16, v);
    }
    __syncthreads();
#pragma unroll
    for (int ks = 0; ks < 2; ++ks) {
      const int cbq = (hc * 64 + ks * 32 + lq * 8) * 2;
      const int cb  = (ks * 32 + lq * 8) * 2;
      bf16x8 a[4], bb[4];
#pragma unroll
      for (int mf = 0; mf < 4; ++mf) a[mf] = lds_frag(Qs, mf * 16 + lr, 512, cbq);
#pragma unroll
      for (int nf = 0; nf < 4; ++nf) bb[nf] = lds_frag(KVs, wid * 64 + nf * 16 + lr, 128, cb);
#pragma unroll
      for (int mf = 0; mf < 4; ++mf)
#pragma unroll
        for (int nf = 0; nf < 4; ++nf)
          acc[mf][nf] = MFMA(a[mf], bb[nf], acc[mf][nf]);
    }
    __syncthreads();
  }

  // ---- causal j-blocks ----
  for (int jb = 0; jb <= bx; ++jb) {
    const int j0 = jb * 64;
    // stage K tile [64 j][256 h]
#pragma unroll
    for (int it = 0; it < 8; ++it) {
      int chunk = t + it * 256;
      int row = chunk >> 5, kg = chunk & 31;
      short8 v = *(const short8*)(kws + ((size_t)(bC + j0 + row) * Hn + kg * 8) * 2);
      lds_put_s8(KVs, row, 512, kg * 16, v);
    }
    __syncthreads();

    // S = Q K^T : wave wid computes S[:, wid*16 .. wid*16+15], K=256
    f32x4 sa[4];
#pragma unroll
    for (int i = 0; i < 4; ++i) sa[i] = f32x4{0.f, 0.f, 0.f, 0.f};
#pragma unroll
    for (int ks = 0; ks < 8; ++ks) {
      const int cb = (ks * 32 + lq * 8) * 2;
      bf16x8 bk = lds_frag(KVs, wid * 16 + lr, 512, cb);
#pragma unroll
      for (int mf = 0; mf < 4; ++mf) {
        bf16x8 aq = lds_frag(Qs, mf * 16 + lr, 512, cb);
        sa[mf] = MFMA(aq, bk, sa[mf]);
      }
    }
    // causal mask (diagonal block only) + store S as bf16
    const int jl = wid * 16 + lr;
#pragma unroll
    for (int mf = 0; mf < 4; ++mf)
#pragma unroll
      for (int r = 0; r < 4; ++r) {
        const int il = mf * 16 + lq * 4 + r;
        float v = sa[mf][r];
        if (jb == bx && jl > il) v = 0.f;
        *(__bf16*)(Ss + il * 128 + ((jl * 2) ^ ((il & 7) << 4))) = (__bf16)v;
      }
    __syncthreads();

    // stage VT tile [256 d][64 j]
#pragma unroll
    for (int it = 0; it < 8; ++it) {
      int chunk = t + it * 256;
      int row = chunk >> 3, kg = chunk & 7;
      short8 v = *(const short8*)(vtws + ((size_t)row * Cn + j0 + kg * 8) * 2);
      lds_put_s8(KVs, row, 128, kg * 16, v);
    }
    __syncthreads();

    // O += S @ V : A from Ss, B from VT tile
#pragma unroll
    for (int ks = 0; ks < 2; ++ks) {
      const int cb = (ks * 32 + lq * 8) * 2;
      bf16x8 a[4], bb[4];
#pragma unroll
      for (int mf = 0; mf < 4; ++mf) a[mf] = lds_frag(Ss, mf * 16 + lr, 128, cb);
#pragma unroll
      for (int nf = 0; nf < 4; ++nf) bb[nf] = lds_frag(KVs, wid * 64 + nf * 16 + lr, 128, cb);
#pragma unroll
      for (int mf = 0; mf < 4; ++mf)
#pragma unroll
        for (int nf = 0; nf < 4; ++nf)
          acc[mf][nf] = MFMA(a[mf], bb[nf], acc[mf][nf]);
    }
    __syncthreads();
  }

  // epilogue: out0[b, i0+il, d]
  float* o0 = out + ((size_t)bC + i0) * Hn;
#pragma unroll
  for (int mf = 0; mf < 4; ++mf)
#pragma unroll
    for (int nf = 0; nf < 4; ++nf) {
      const int d = wid * 64 + nf * 16 + lr;
#pragma unroll
      for (int r = 0; r < 4; ++r) {
        const int il = mf * 16 + lq * 4 + r;
        o0[(size_t)il * Hn + d] = acc[mf][nf][r];
      }
    }
}

// ---------------------------------------------------------------------------
extern "C" void kernel_launch(void* const* d_in, const int* in_sizes, int n_in,
                              void* d_out, int out_size, void* d_ws, size_t ws_size,
                              hipStream_t stream)
{
  const float* key    = (const float*)d_in[0];
  const float* query  = (const float*)d_in[1];
  const float* value  = (const float*)d_in[2];
  const float* hstate = (const float*)d_in[3];
  // d_in[4] = dones: unused (its only effect is scaled by kappa^256 ~= 2e-12)
  const float* wq = (const float*)d_in[5];
  const float* wk = (const float*)d_in[6];
  const float* wv = (const float*)d_in[7];

  char*  ws  = (char*)d_ws;
  float* out = (float*)d_out;

  proj_kernel<<<dim3(256, 3), 512, 0, stream>>>(query, key, value, wq, wk, wv, ws);
  transpose_h<<<4096, 256, 0, stream>>>(hstate, ws);
  hstate_kernel<<<64, 256, 0, stream>>>(ws, out);
  attn_kernel<<<dim3(32, 16), 256, 0, stream>>>(ws, out);
}